// Round 10
// baseline (799.383 us; speedup 1.0000x reference)
//
#include <hip/hip_runtime.h>
#include <hip/hip_bf16.h>
#include <math.h>

// R10: R9 + (a) merged P4+P5 with redundant full-N phi_z in wave-private LDS
// (drops barrier B4; 4 barriers/step), (b) KL moved to H-waves (qm/qs/lqs stay
// in H registers; X-P3 transcendental-free), (c) single prep kernel
// (zero+pack+phix merged; phix barrier-free + prefetch).
// 64 blocks x 16 rows, 8 waves. eps ~= 0 approximation unchanged (R1-R9).

#define TT   128
#define NZN  5
#define ADIM 20
#define ROWS 16
#define FRW  40
#define PS   68
#define PHIX_OFF (8 * FRW * 64 * 8)   // shorts = 163840

typedef __attribute__((ext_vector_type(8))) short short8;
typedef __attribute__((ext_vector_type(4))) float f32x4;

__device__ __forceinline__ float reluf(float x) { return fmaxf(x, 0.f); }
__device__ __forceinline__ float frcp(float x)  { return __builtin_amdgcn_rcpf(x); }
__device__ __forceinline__ float fexp(float x)  { return __expf(x); }
__device__ __forceinline__ float flog(float x)  { return __logf(x); }
__device__ __forceinline__ float fsigm(float x) { return frcp(1.f + fexp(-x)); }
__device__ __forceinline__ float ftanh(float x) {
    float cx = fminf(fmaxf(x, -15.f), 15.f);
    float e2 = fexp(2.f * cx);
    return 1.f - 2.f * frcp(e2 + 1.f);
}
__device__ __forceinline__ float fsoftplus(float x) {
    return fmaxf(x, 0.f) + flog(1.f + fexp(-fabsf(x)));
}
__device__ __forceinline__ unsigned int pk2bf(float lo, float hi) {
    unsigned int r;
    asm volatile("v_cvt_pk_bf16_f32 %0, %1, %2" : "=v"(r) : "v"(lo), "v"(hi));
    return r;
}
__device__ __forceinline__ void stage2(short* buf, int shift, int rw0, int col,
                                       float v0, float v1) {
    unsigned int u = pk2bf(v0, v1);
    buf[(rw0 << shift) + (col ^ ((rw0 & 7) << 3))]             = (short)(u & 0xffff);
    buf[((rw0 + 1) << shift) + (col ^ (((rw0 + 1) & 7) << 3))] = (short)(u >> 16);
}
__device__ __forceinline__ short8 lda64(const short* b, int c, int col0) {
    return *(const short8*)(b + c * 64 + (col0 ^ ((c & 7) << 3)));
}
__device__ __forceinline__ short8 lda128(const short* b, int c, int col0) {
    return *(const short8*)(b + c * 128 + (col0 ^ ((c & 7) << 3)));
}
__device__ __forceinline__ unsigned short f2bf(float x) {
    union { float f; unsigned int u; } v; v.f = x;
    unsigned int r = v.u + 0x7fffu + ((v.u >> 16) & 1u);
    return (unsigned short)(r >> 16);
}
__device__ __forceinline__ float wave_sum64(float v) {
#pragma unroll
    for (int off = 32; off > 0; off >>= 1) v += __shfl_xor(v, off, 64);
    return v;
}
#define MFMA(a, b, acc) __builtin_amdgcn_mfma_f32_16x16x32_bf16((a), (b), (acc), 0, 0, 0)

// ================= unified prep: zero + pack + phix =================
// blocks 0..79: pack fragment streams (8 waves x 40 frags).
// blocks 80..591: phi_x precompute (barrier-free inner loop, prefetch).
__global__ __launch_bounds__(256) void prep_all(
    const int* __restrict__ acts, const float* __restrict__ durs,
    const float* __restrict__ W_act, const float* __restrict__ b_act,
    const float* __restrict__ W_dur, const float* __restrict__ b_dur,
    const float* __restrict__ W_x,  const float* __restrict__ b_x,
    const float* __restrict__ Wp1, const float* __restrict__ Wq1,
    const float* __restrict__ Wp2, const float* __restrict__ Wq2,
    const float* __restrict__ W_z, const float* __restrict__ W_ih,
    const float* __restrict__ W_hh,
    short* __restrict__ ws, float* __restrict__ out)
{
    __shared__ float sWx[8192];
    __shared__ float scat[4][128];

    if (blockIdx.x == 0 && threadIdx.x == 0) out[22528] = 0.f;

    if (blockIdx.x < 80) {
        // ---------------- pack ----------------
        const int tid = blockIdx.x * 256 + threadIdx.x;   // < 8*40*64
        const int l = tid & 63, f = (tid >> 6) % FRW, w = (tid >> 6) / FRW;
        const int cc = l & 15, gg = l >> 4;
        const float* src = nullptr; int ld = 64, ncol = 0, k0 = 0;
        if (w < 4) {  // X stream
            const int fcp = 16 * w + cc;
            if (f < 16)      { int n = f >> 2, q = f & 3;
                               src = Wp1 + n * 8192; k0 = 32 * q; ncol = fcp; }
            else if (f < 26) { int r = f - 16; int n = r >> 1, q = r & 1;
                               src = Wp2 + n * 4096; k0 = 32 * q; ncol = fcp; }
            else if (f < 34) { int r = f - 26; int s = r >> 1, q = r & 1;
                               src = W_z; k0 = 32 * q; ncol = 16 * s + cc; }
            else             { int r = f - 34; int gt = r >> 1, q = r & 1;
                               src = W_ih; ld = 192; ncol = gt * 64 + fcp; k0 = 64 + 32 * q; }
        } else {      // H stream
            const int fcp = 16 * (w - 4) + cc; ncol = fcp;
            if (f < 10)      { int n = f >> 1, q = f & 1;
                               src = Wq1 + n * 4096; k0 = 32 * q; }
            else if (f < 16) { int r = f - 10; int gt = r >> 1, q = r & 1;
                               src = W_hh; ld = 192; ncol = gt * 64 + fcp; k0 = 32 * q; }
            else if (f < 20) { src = Wp1 + 4 * 8192; k0 = 32 * (f - 16); }
            else if (f < 30) { int r = f - 20; int n = r >> 1, q = r & 1;
                               src = Wq2 + n * 4096; k0 = 32 * q; }
            else if (f < 36) { int r = f - 30; int gt = r >> 1, q = r & 1;
                               src = W_ih; ld = 192; ncol = gt * 64 + fcp; k0 = 32 * q; }
            // f 36..39: zero pad
        }
        short8 frag = {0, 0, 0, 0, 0, 0, 0, 0};
        if (src) {
#pragma unroll
            for (int j = 0; j < 8; ++j)
                frag[j] = (short)f2bf(src[(k0 + 8 * gg + j) * ld + ncol]);
        }
        *(short8*)(ws + ((w * FRW + f) * 64 + l) * 8) = frag;
        return;
    }

    // ---------------- phi_x precompute ----------------
    const int pb = blockIdx.x - 80;          // 0..511
    const int blk = pb >> 3, tch = pb & 7;
    const int v = threadIdx.x >> 6, l = threadIdx.x & 63;
    short* __restrict__ phix = ws + PHIX_OFF;
    for (int e = threadIdx.x; e < 8192; e += 256) sWx[e] = W_x[e];
    const float bact = b_act[l], wdur = W_dur[l], bdur = b_dur[l], bx = b_x[l];
    __syncthreads();
    // wave v handles pp = v*64 + u ; t = tch*16 + (pp>>4), r = pp&15
    int a_n; float d_n;
    {
        const int pp = v * 64;
        const int t0 = tch * 16 + (pp >> 4), b0 = blk * 16 + (pp & 15);
        a_n = acts[b0 * TT + t0]; d_n = durs[b0 * TT + t0];
    }
    for (int u = 0; u < 64; ++u) {
        const int pp = v * 64 + u;
        const int t = tch * 16 + (pp >> 4);
        const int r = pp & 15;
        const int a = a_n; const float dur = d_n;
        if (u < 63) {
            const int pp2 = pp + 1;
            const int t2 = tch * 16 + (pp2 >> 4), b2 = blk * 16 + (pp2 & 15);
            a_n = acts[b2 * TT + t2]; d_n = durs[b2 * TT + t2];
        }
        scat[v][l]      = reluf(W_act[a * 64 + l] + bact);
        scat[v][64 + l] = reluf(fmaf(dur, wdur, bdur));
        // wave-local LDS dependency: compiler-inserted lgkmcnt orders this
        float phi = bx;
#pragma unroll 8
        for (int i = 0; i < 128; ++i)
            phi = fmaf(scat[v][i], sWx[i * 64 + l], phi);
        phix[((t * 64 + blk) * 16 + r) * 64 + (l ^ ((r & 7) << 3))] =
            (short)f2bf(reluf(phi));
    }
}

__global__ __launch_bounds__(512, 1) void vrnn_main(
    const float* __restrict__ W_act, const float* __restrict__ b_act,
    const float* __restrict__ b_z,
    const float* __restrict__ bp1, const float* __restrict__ bq1,
    const float* __restrict__ bp2, const float* __restrict__ bq2,
    const float* __restrict__ b_ih, const float* __restrict__ b_hh,
    const float* __restrict__ g_post, const float* __restrict__ g_prior,
    const float* __restrict__ Wq1, const float* __restrict__ Wq2,
    const float* __restrict__ W_z, const float* __restrict__ W_dec,
    const float* __restrict__ b_dec, const float* __restrict__ W_a,
    const float* __restrict__ b_a, const float* __restrict__ W_durd,
    const float* __restrict__ b_durd,
    const short* __restrict__ ws, float* __restrict__ d_out)
{
    const int w = threadIdx.x >> 6, l = threadIdx.x & 63;
    const bool isH = (w >= 4);
    const int ns = isH ? (w - 4) : w;
    const int g = l >> 4, c = l & 15;
    const int fc = 16 * ns + c;
    const int row0 = blockIdx.x * ROWS;
    const short* __restrict__ phix = ws + PHIX_OFF;

    __shared__ __align__(16) short s_xz[ROWS * 128];
    __shared__ __align__(16) short s_h[ROWS * 64];
    __shared__ __align__(16) short s_h1p[NZN][ROWS * 64];  // epilogue: aliased as s_fin
    __shared__ __align__(16) short s_h1q[NZN][ROWS * 64];  // P4': waves' private phi_z
    __shared__ __align__(16) short s_z[ROWS * 64];
    __shared__ float s_gh[3][ROWS * PS];
    __shared__ float s_gix[3][ROWS * PS];
    __shared__ float s_mp[ROWS * PS];                      // mpost f32 (X->H)
    __shared__ float s_hf[ROWS * 64];
    __shared__ float s_klsum[ROWS];

    const short8* Bw = ((const short8*)ws) + (w * FRW) * 64 + l;
#define BF(f) Bw[(f) * 64]
    const f32x4 Z4 = {0.f, 0.f, 0.f, 0.f};

    // wave-role bias unions
    float b1r[NZN], gam[NZN];
    float c2 = 0.f, bA = 0.f;
    float bzv[4] = {0.f, 0.f, 0.f, 0.f};
    if (!isH) {
#pragma unroll
        for (int n = 0; n < NZN; ++n) {
            gam[n] = g_post[n];
            b1r[n] = bp1[n * 64 + fc];
            c2 = fmaf(gam[n], bp2[n * 64 + fc], c2);
        }
#pragma unroll
        for (int s = 0; s < 4; ++s) bzv[s] = b_z[16 * s + c];
    } else {
#pragma unroll
        for (int n = 0; n < NZN; ++n) {
            gam[n] = g_prior[n];
            b1r[n] = bq1[n * 64 + fc];
            c2 = fmaf(gam[n], bq2[n * 64 + fc], c2);
        }
        bA = bp1[4 * 64 + fc];     // posterior net4 L1 bias
    }
    const float bih0 = b_ih[fc], bih1 = b_ih[64 + fc], bih2 = b_ih[128 + fc];
    const float bhh0 = b_hh[fc], bhh1 = b_hh[64 + fc], bhh2 = b_hh[128 + fc];

    float hr[4]  = {0.f, 0.f, 0.f, 0.f};   // X: hidden state rows 4g+r
    float kl[4]  = {0.f, 0.f, 0.f, 0.f};   // H: KL accum
    float qmr[4], qsr[4], lqr[4];           // H: prior stats (registers)

    for (int i = threadIdx.x; i < ROWS * 64; i += 512) s_h[i] = 0;
    if (threadIdx.x < ROWS) s_klsum[threadIdx.x] = 0.f;

    short8 ax0, ax1, ah0, ah1;

    for (int t = 0; t < TT; ++t) {
        __syncthreads();                                        // B0
        if (!isH) {
            // ---- P1-X: copy precomputed pre-swizzled phi_x tile ----
            const int idx = w * 64 + l;
            const int r  = idx >> 4;
            const int c0 = (idx & 15) * 4;
            const uint2* src = (const uint2*)(phix + (size_t)(t * 64 + blockIdx.x) * 1024);
            uint2 val = src[idx];
            *(uint2*)(s_xz + r * 128 + c0) = val;
        } else {
            // ---- P1-H: prior L1 + gh ----
            ah0 = lda64(s_h, c, 8 * g);
            ah1 = lda64(s_h, c, 32 + 8 * g);
#pragma unroll
            for (int n = 0; n < NZN; ++n) {
                f32x4 q = MFMA(ah0, BF(2 * n), Z4);
                q = MFMA(ah1, BF(2 * n + 1), q);
                stage2(s_h1q[n], 6, 4 * g,     fc, reluf(q[0] + b1r[n]), reluf(q[1] + b1r[n]));
                stage2(s_h1q[n], 6, 4 * g + 2, fc, reluf(q[2] + b1r[n]), reluf(q[3] + b1r[n]));
            }
#pragma unroll
            for (int gt = 0; gt < 3; ++gt) {
                f32x4 gh = MFMA(ah0, BF(10 + 2 * gt), Z4);
                gh = MFMA(ah1, BF(11 + 2 * gt), gh);
#pragma unroll
                for (int r = 0; r < 4; ++r)
                    s_gh[gt][(4 * g + r) * PS + fc] = gh[r];
            }
        }
        __syncthreads();                                        // B1
        if (!isH) {
            // ---- P2-X: post L1 nets 0-3 ----
            ax0 = lda128(s_xz, c, 8 * g);
            ax1 = lda128(s_xz, c, 32 + 8 * g);
            ah0 = lda64(s_h, c, 8 * g);
            ah1 = lda64(s_h, c, 32 + 8 * g);
#pragma unroll
            for (int n = 0; n < 4; ++n) {
                f32x4 p = MFMA(ax0, BF(4 * n + 0), Z4);
                p = MFMA(ax1, BF(4 * n + 1), p);
                p = MFMA(ah0, BF(4 * n + 2), p);
                p = MFMA(ah1, BF(4 * n + 3), p);
                stage2(s_h1p[n], 6, 4 * g,     fc, reluf(p[0] + b1r[n]), reluf(p[1] + b1r[n]));
                stage2(s_h1p[n], 6, 4 * g + 2, fc, reluf(p[2] + b1r[n]), reluf(p[3] + b1r[n]));
            }
        } else {
            // ---- P2-H: post L1 net4 + prior L2 (stats -> registers) ----
            ax0 = lda128(s_xz, c, 8 * g);
            ax1 = lda128(s_xz, c, 32 + 8 * g);
            {
                f32x4 p = MFMA(ax0, BF(16), Z4);
                p = MFMA(ax1, BF(17), p);
                p = MFMA(ah0, BF(18), p);
                p = MFMA(ah1, BF(19), p);
                stage2(s_h1p[4], 6, 4 * g,     fc, reluf(p[0] + bA), reluf(p[1] + bA));
                stage2(s_h1p[4], 6, 4 * g + 2, fc, reluf(p[2] + bA), reluf(p[3] + bA));
            }
            f32x4 mq = Z4;
#pragma unroll
            for (int n = 0; n < NZN; ++n) {
                short8 hq0 = lda64(s_h1q[n], c, 8 * g);
                short8 hq1 = lda64(s_h1q[n], c, 32 + 8 * g);
                f32x4 q = MFMA(hq0, BF(20 + 2 * n), Z4);
                q = MFMA(hq1, BF(21 + 2 * n), q);
#pragma unroll
                for (int r = 0; r < 4; ++r) mq[r] = fmaf(gam[n], q[r], mq[r]);
            }
#pragma unroll
            for (int r = 0; r < 4; ++r) {
                float mpri = mq[r] + c2;
                qmr[r] = reluf(mpri);
                qsr[r] = fsoftplus(mpri);
                lqr[r] = flog(qsr[r]);
            }
        }
        __syncthreads();                                        // B2
        if (!isH) {
            // ---- P3-X: post L2 + gamma -> mpost (f32), z (no transcendentals) ----
            f32x4 mp = Z4;
#pragma unroll
            for (int n = 0; n < NZN; ++n) {
                short8 hp0 = lda64(s_h1p[n], c, 8 * g);
                short8 hp1 = lda64(s_h1p[n], c, 32 + 8 * g);
                f32x4 p = MFMA(hp0, BF(16 + 2 * n), Z4);
                p = MFMA(hp1, BF(17 + 2 * n), p);
#pragma unroll
                for (int r = 0; r < 4; ++r) mp[r] = fmaf(gam[n], p[r], mp[r]);
            }
            float pmv[4];
#pragma unroll
            for (int r = 0; r < 4; ++r) {
                const int rw = 4 * g + r;
                float mpost = mp[r] + c2;
                s_mp[rw * PS + fc] = mpost;
                pmv[r] = reluf(mpost);
            }
            stage2(s_z, 6, 4 * g,     fc, pmv[0], pmv[1]);
            stage2(s_z, 6, 4 * g + 2, fc, pmv[2], pmv[3]);
        } else {
            // ---- P3-H: gi_x ----
#pragma unroll
            for (int gt = 0; gt < 3; ++gt) {
                f32x4 gx = MFMA(ax0, BF(30 + 2 * gt), Z4);
                gx = MFMA(ax1, BF(31 + 2 * gt), gx);
#pragma unroll
                for (int r = 0; r < 4; ++r)
                    s_gix[gt][(4 * g + r) * PS + fc] = gx[r];
            }
        }
        __syncthreads();                                        // B3
        if (!isH) {
            // ---- P4'-X: full-N phi_z (private) + gi_z + GRU ----
            short* priv = ((short*)s_h1q) + ns * 1024;   // wave-private 16x64
            short8 az0 = lda64(s_z, c, 8 * g);
            short8 az1 = lda64(s_z, c, 32 + 8 * g);
#pragma unroll
            for (int s = 0; s < 4; ++s) {
                f32x4 zz = MFMA(az0, BF(26 + 2 * s), Z4);
                zz = MFMA(az1, BF(27 + 2 * s), zz);
                stage2(priv, 6, 4 * g,     16 * s + c, reluf(zz[0] + bzv[s]), reluf(zz[1] + bzv[s]));
                stage2(priv, 6, 4 * g + 2, 16 * s + c, reluf(zz[2] + bzv[s]), reluf(zz[3] + bzv[s]));
            }
            // wave-local read-back (compiler orders via lgkmcnt)
            short8 gz0 = lda64(priv, c, 8 * g);
            short8 gz1 = lda64(priv, c, 32 + 8 * g);
            f32x4 gi0 = MFMA(gz0, BF(34), Z4); gi0 = MFMA(gz1, BF(35), gi0);
            f32x4 gi1 = MFMA(gz0, BF(36), Z4); gi1 = MFMA(gz1, BF(37), gi1);
            f32x4 gi2 = MFMA(gz0, BF(38), Z4); gi2 = MFMA(gz1, BF(39), gi2);
#pragma unroll
            for (int r = 0; r < 4; ++r) {
                const int rw = 4 * g + r;
                float i0 = gi0[r] + s_gix[0][rw * PS + fc] + bih0;
                float i1 = gi1[r] + s_gix[1][rw * PS + fc] + bih1;
                float i2 = gi2[r] + s_gix[2][rw * PS + fc] + bih2;
                float h0 = s_gh[0][rw * PS + fc] + bhh0;
                float h1 = s_gh[1][rw * PS + fc] + bhh1;
                float h2 = s_gh[2][rw * PS + fc] + bhh2;
                float rr = fsigm(i0 + h0);
                float zg = fsigm(i1 + h1);
                float nn = ftanh(i2 + rr * h2);
                hr[r] = (1.f - zg) * nn + zg * hr[r];
            }
            stage2(s_h, 6, 4 * g,     fc, hr[0], hr[1]);
            stage2(s_h, 6, 4 * g + 2, fc, hr[2], hr[3]);
        } else {
            // ---- P4'-H: KL from mpost + register prior stats ----
#pragma unroll
            for (int r = 0; r < 4; ++r) {
                const int rw = 4 * g + r;
                float mpost = s_mp[rw * PS + fc];
                float pm = reluf(mpost), ps = fsoftplus(mpost);
                float dd = pm - qmr[r];
                kl[r] += lqr[r] - flog(ps)
                       + (ps * ps + dd * dd) * 0.5f * frcp(qsr[r] * qsr[r]) - 0.5f;
            }
        }
    }

    // ================= epilogue =================
    if (!isH) {
#pragma unroll
        for (int r = 0; r < 4; ++r) s_hf[(4 * g + r) * 64 + fc] = hr[r];
    } else {
#pragma unroll
        for (int off = 1; off < 16; off <<= 1) {
#pragma unroll
            for (int r = 0; r < 4; ++r) kl[r] += __shfl_xor(kl[r], off, 64);
        }
        if (c == 0) {
#pragma unroll
            for (int r = 0; r < 4; ++r) atomicAdd(&s_klsum[4 * g + r], kl[r]);
        }
    }
    __syncthreads();

    // final decode: wave w handles rows 2w, 2w+1 (fp32 original weights)
    {
        float gqe[NZN];
#pragma unroll
        for (int n = 0; n < NZN; ++n) gqe[n] = g_prior[n];
        float* sf = ((float*)s_h1p) + w * 320;          // aliased: s_h1p is dead
        for (int rr = 0; rr < 2; ++rr) {
            const int lr = 2 * w + rr, grow = row0 + lr;
            float accn[NZN];
#pragma unroll
            for (int n = 0; n < NZN; ++n) accn[n] = bq1[n * 64 + l];
            for (int i = 0; i < 64; ++i) {
                const float hv = s_hf[lr * 64 + i];
#pragma unroll
                for (int n = 0; n < NZN; ++n) accn[n] += hv * Wq1[(n * 64 + i) * 64 + l];
            }
#pragma unroll
            for (int n = 0; n < NZN; ++n) sf[n * 64 + l] = reluf(accn[n]);
            float u[NZN];
#pragma unroll
            for (int n = 0; n < NZN; ++n) u[n] = bq2[n * 64 + l];
            for (int o = 0; o < 64; ++o) {
#pragma unroll
                for (int n = 0; n < NZN; ++n) u[n] += sf[n * 64 + o] * Wq2[(n * 64 + o) * 64 + l];
            }
            float mpri = 0.f;
#pragma unroll
            for (int n = 0; n < NZN; ++n) mpri = fmaf(gqe[n], u[n], mpri);
            sf[l] = reluf(mpri);                       // z
            float za = b_z[l];
            for (int i = 0; i < 64; ++i) za += sf[i] * W_z[i * 64 + l];
            sf[64 + l] = reluf(za);                    // phi_z
            float dv = b_dec[l];
            for (int i = 0; i < 64; ++i) {
                dv += sf[64 + i] * W_dec[i * 64 + l];
                dv += s_hf[lr * 64 + i] * W_dec[(64 + i) * 64 + l];
            }
            const float dec = reluf(dv);
            sf[128 + l] = dec;
            float lg = 0.f;
            if (l < ADIM) {
                lg = b_a[l];
                for (int o = 0; o < 64; ++o) lg += sf[128 + o] * W_a[o * ADIM + l];
                d_out[grow * ADIM + l] = lg;           // output 0
                sf[192 + l] = lg;
            }
            float pl = b_act[l];
#pragma unroll
            for (int j = 0; j < ADIM; ++j) pl += sf[192 + j] * W_act[j * 64 + l];
            pl = reluf(pl);
            float contrib = pl * W_durd[l] + dec * W_durd[64 + l];
            contrib = wave_sum64(contrib);
            if (l == 0) {
                const float dd = contrib + b_durd[0];
                d_out[20480 + grow] = dd;              // output 1
                d_out[21504 + grow] = fsoftplus(dd);   // output 2
            }
        }
    }
    if (threadIdx.x == 0) {
        float s = 0.f;
#pragma unroll
        for (int i = 0; i < ROWS; ++i) s += s_klsum[i];
        atomicAdd(d_out + 22528, s * (1.f / 1024.f));  // output 3
    }
#undef BF
}

extern "C" void kernel_launch(void* const* d_in, const int* in_sizes, int n_in,
                              void* d_out, int out_size, void* d_ws, size_t ws_size,
                              hipStream_t stream)
{
    const int*   acts    = (const int*)  d_in[0];
    const float* durs    = (const float*)d_in[1];
    const float* W_act   = (const float*)d_in[2];
    const float* b_act   = (const float*)d_in[3];
    const float* W_dur   = (const float*)d_in[4];
    const float* b_dur   = (const float*)d_in[5];
    const float* W_x     = (const float*)d_in[6];
    const float* b_x     = (const float*)d_in[7];
    const float* W_z     = (const float*)d_in[8];
    const float* b_z     = (const float*)d_in[9];
    const float* Wp1     = (const float*)d_in[10];
    const float* bp1     = (const float*)d_in[11];
    const float* Wp2     = (const float*)d_in[12];
    const float* bp2     = (const float*)d_in[13];
    const float* Wq1     = (const float*)d_in[14];
    const float* bq1     = (const float*)d_in[15];
    const float* Wq2     = (const float*)d_in[16];
    const float* bq2     = (const float*)d_in[17];
    const float* W_dec   = (const float*)d_in[18];
    const float* b_dec   = (const float*)d_in[19];
    const float* W_a     = (const float*)d_in[20];
    const float* b_a     = (const float*)d_in[21];
    const float* W_durd  = (const float*)d_in[22];
    const float* b_durd  = (const float*)d_in[23];
    const float* W_ih    = (const float*)d_in[24];
    const float* W_hh    = (const float*)d_in[25];
    const float* b_ih    = (const float*)d_in[26];
    const float* b_hh    = (const float*)d_in[27];
    const float* g_post  = (const float*)d_in[28];
    const float* g_prior = (const float*)d_in[29];
    float* out = (float*)d_out;
    short* ws  = (short*)d_ws;

    prep_all<<<592, 256, 0, stream>>>(acts, durs, W_act, b_act, W_dur, b_dur,
                                      W_x, b_x, Wp1, Wq1, Wp2, Wq2, W_z, W_ih,
                                      W_hh, ws, out);
    vrnn_main<<<64, 512, 0, stream>>>(
        W_act, b_act, b_z, bp1, bq1, bp2, bq2, b_ih, b_hh, g_post, g_prior,
        Wq1, Wq2, W_z, W_dec, b_dec, W_a, b_a, W_durd, b_durd,
        ws, out);
}